// Round 13
// baseline (2738.931 us; speedup 1.0000x reference)
//
#include <hip/hip_runtime.h>
#include <math.h>

// Problem constants (fixed by the reference)
#define NN 10000
#define EE 160000
#define FF 128
#define RR 20
#define LL 3
#define CUTOFF 3.0f
#define F3 384           // 3*F
#define PI_F 3.14159265358979323846f

// Round-4 lesson: never pass accumulator arrays to helpers (pointer decay ->
// scratch). Round-7 lessons: (a) keep full-384 features per wave for max
// outstanding gathers; (b) rbf contraction must feed >=4 FMAs per LDS read;
// (c) GEMM weights belong in LDS (shared), A as wave-broadcast L1-hit loads.

// ---------------------------------------------------------------------------
// init: sfeat = emb[z], v = 0, deg = 0
__global__ __launch_bounds__(256) void k_init(const int* __restrict__ z,
                                              const float* __restrict__ emb,
                                              float* __restrict__ sfeat,
                                              float* __restrict__ v,
                                              int* __restrict__ deg) {
    int idx = blockIdx.x * 256 + threadIdx.x;
    if (idx < NN * 3 * FF) v[idx] = 0.f;
    if (idx < NN * FF) {
        int n = idx >> 7, f = idx & 127;
        sfeat[idx] = emb[z[n] * FF + f];
    }
    if (idx < NN) deg[idx] = 0;
}

// ---------------------------------------------------------------------------
// CSR build over LIVE edges (dist^2 < CUT^2): count, scan, fill, permute
__global__ __launch_bounds__(256) void k_count(const int* __restrict__ idx_i,
                                               const int* __restrict__ idx_j,
                                               const float* __restrict__ pos,
                                               int* __restrict__ deg) {
    int e = blockIdx.x * 256 + threadIdx.x;
    if (e >= EE) return;
    int i = idx_i[e], j = idx_j[e];
    float dx = pos[j * 3 + 0] - pos[i * 3 + 0];
    float dy = pos[j * 3 + 1] - pos[i * 3 + 1];
    float dz = pos[j * 3 + 2] - pos[i * 3 + 2];
    float sq = dx * dx + dy * dy + dz * dz;
    if (sq < CUTOFF * CUTOFF) atomicAdd(&deg[i], 1);
}

__global__ __launch_bounds__(1024) void k_scan(const int* __restrict__ deg,
                                               int* __restrict__ rowstart,
                                               int* __restrict__ cursor) {
    __shared__ int sd[1024];
    __shared__ int carry;
    if (threadIdx.x == 0) carry = 0;
    __syncthreads();
    for (int base = 0; base < NN; base += 1024) {
        int i = base + (int)threadIdx.x;
        int val = (i < NN) ? deg[i] : 0;
        sd[threadIdx.x] = val;
        __syncthreads();
        for (int off = 1; off < 1024; off <<= 1) {
            int t = (threadIdx.x >= off) ? sd[threadIdx.x - off] : 0;
            __syncthreads();
            sd[threadIdx.x] += t;
            __syncthreads();
        }
        if (i < NN) {
            int ex = carry + sd[threadIdx.x] - val;   // exclusive prefix
            rowstart[i] = ex;
            cursor[i] = ex;
        }
        __syncthreads();
        if (threadIdx.x == 0) carry += sd[1023];
        __syncthreads();
    }
    if (threadIdx.x == 0) rowstart[NN] = carry;
}

__global__ __launch_bounds__(256) void k_fill(const int* __restrict__ idx_i,
                                              const int* __restrict__ idx_j,
                                              const float* __restrict__ pos,
                                              int* __restrict__ cursor,
                                              int* __restrict__ eids) {
    int e = blockIdx.x * 256 + threadIdx.x;
    if (e >= EE) return;
    int i = idx_i[e], j = idx_j[e];
    float dx = pos[j * 3 + 0] - pos[i * 3 + 0];
    float dy = pos[j * 3 + 1] - pos[i * 3 + 1];
    float dz = pos[j * 3 + 2] - pos[i * 3 + 2];
    float sq = dx * dx + dy * dy + dz * dz;
    if (sq < CUTOFF * CUTOFF) {
        int p = atomicAdd(&cursor[i], 1);
        eids[p] = e;
    }
}

// Materialize CSR payloads: j, (cut,dir), rbf per live slot.
__global__ __launch_bounds__(256) void k_permute(const int* __restrict__ idx_i,
                                                 const int* __restrict__ idx_j,
                                                 const float* __restrict__ pos,
                                                 const int* __restrict__ eids,
                                                 const int* __restrict__ rowstart,
                                                 int* __restrict__ j_csr,
                                                 float4* __restrict__ cd_csr,
                                                 float* __restrict__ rbf_csr) {
    int t = blockIdx.x * 256 + threadIdx.x;
    if (t >= rowstart[NN]) return;
    int e = eids[t];
    int i = idx_i[e], j = idx_j[e];
    float dx = pos[j * 3 + 0] - pos[i * 3 + 0];
    float dy = pos[j * 3 + 1] - pos[i * 3 + 1];
    float dz = pos[j * 3 + 2] - pos[i * 3 + 2];
    float sq = dx * dx + dy * dy + dz * dz;
    float dist = sq > 0.f ? sqrtf(sq) : 0.f;
    float inv = dist > 0.f ? 1.f / dist : 0.f;
    float cut = 0.5f * (cosf(PI_F * dist / CUTOFF) + 1.f);
    j_csr[t] = j;
    cd_csr[t] = make_float4(cut, dx * inv, dy * inv, dz * inv);
    float b = PI_F * dist / CUTOFF;
    float* rp = rbf_csr + (size_t)t * RR;
#pragma unroll
    for (int r = 0; r < RR; r++)
        rp[r] = sinf((float)(r + 1) * b) * inv;
}

// ---------------------------------------------------------------------------
// Generic fp32 GEMM, weight-stationary-in-LDS. C[:,strip] = act(A_cat@W + b)
// A_cat rows = A[row,0:KA] ++ A2[row,0:KTOT-KA]  (A2 null iff KA==KTOT)
// Block 256 thr: ROWS rows x 128 cols; thread: RT=ROWS/8 rows x 4 cols.
// W staged in LDS per 32-k chunk (16.9 KB); A read as wave-broadcast dword
// loads (2 addrs/wave, rows stay L1-hot) — avoids the L1 weight-thrash that
// held the round-7 GEMMs at ~12% VALU.
template <int KTOT, int ROWS, bool SILU>
__global__ __launch_bounds__(256, 4) void k_mlp(const float* __restrict__ A, int KA,
                                                const float* __restrict__ A2,
                                                const float* __restrict__ W,
                                                const float* __restrict__ bias,
                                                float* __restrict__ C, int M, int NOUT) {
    constexpr int RT = ROWS / 8;         // rows per thread: 4 or 8
    __shared__ float Ws[32 * 132];
    const int tid = threadIdx.x;
    const int cg = tid & 31, rg = tid >> 5;
    const int cbase = blockIdx.y * 128;
    const int c0 = cbase + cg * 4;
    const int r0 = blockIdx.x * ROWS + rg * RT;
    float4 acc0, acc1, acc2, acc3, acc4, acc5, acc6, acc7;
    {
        float4 b = bias ? *reinterpret_cast<const float4*>(bias + c0)
                        : make_float4(0.f, 0.f, 0.f, 0.f);
        acc0 = b; acc1 = b; acc2 = b; acc3 = b;
        acc4 = b; acc5 = b; acc6 = b; acc7 = b;
    }
    const int K2 = KTOT - KA;
    for (int kc = 0; kc < KTOT; kc += 32) {
        __syncthreads();
        for (int idx = tid; idx < 32 * 128; idx += 256) {
            int kk = idx >> 7, c = idx & 127;
            Ws[kk * 132 + c] = W[(size_t)(kc + kk) * NOUT + cbase + c];
        }
        __syncthreads();
        const float* Ab; int ks, koff;
        if (kc < KA) { Ab = A; ks = KA; koff = 0; }
        else         { Ab = A2; ks = K2; koff = KA; }
        const float* a0 = Ab + (size_t)min(r0 + 0, M - 1) * ks + (kc - koff);
        const float* a1 = Ab + (size_t)min(r0 + 1, M - 1) * ks + (kc - koff);
        const float* a2 = Ab + (size_t)min(r0 + 2, M - 1) * ks + (kc - koff);
        const float* a3 = Ab + (size_t)min(r0 + 3, M - 1) * ks + (kc - koff);
        const float* a4 = a0; const float* a5 = a0;
        const float* a6 = a0; const float* a7 = a0;
        if constexpr (RT == 8) {
            a4 = Ab + (size_t)min(r0 + 4, M - 1) * ks + (kc - koff);
            a5 = Ab + (size_t)min(r0 + 5, M - 1) * ks + (kc - koff);
            a6 = Ab + (size_t)min(r0 + 6, M - 1) * ks + (kc - koff);
            a7 = Ab + (size_t)min(r0 + 7, M - 1) * ks + (kc - koff);
        }
#pragma unroll 4
        for (int kk = 0; kk < 32; kk++) {
            float4 w = *reinterpret_cast<const float4*>(&Ws[kk * 132 + cg * 4]);
            float v0 = a0[kk], v1 = a1[kk], v2 = a2[kk], v3 = a3[kk];
            acc0.x += v0 * w.x; acc0.y += v0 * w.y; acc0.z += v0 * w.z; acc0.w += v0 * w.w;
            acc1.x += v1 * w.x; acc1.y += v1 * w.y; acc1.z += v1 * w.z; acc1.w += v1 * w.w;
            acc2.x += v2 * w.x; acc2.y += v2 * w.y; acc2.z += v2 * w.z; acc2.w += v2 * w.w;
            acc3.x += v3 * w.x; acc3.y += v3 * w.y; acc3.z += v3 * w.z; acc3.w += v3 * w.w;
            if constexpr (RT == 8) {
                float v4 = a4[kk], v5 = a5[kk], v6 = a6[kk], v7 = a7[kk];
                acc4.x += v4 * w.x; acc4.y += v4 * w.y; acc4.z += v4 * w.z; acc4.w += v4 * w.w;
                acc5.x += v5 * w.x; acc5.y += v5 * w.y; acc5.z += v5 * w.z; acc5.w += v5 * w.w;
                acc6.x += v6 * w.x; acc6.y += v6 * w.y; acc6.z += v6 * w.z; acc6.w += v6 * w.w;
                acc7.x += v7 * w.x; acc7.y += v7 * w.y; acc7.z += v7 * w.z; acc7.w += v7 * w.w;
            }
        }
    }
#define STORE_ROW(P, ACC)                                                  \
    if (P < RT && r0 + P < M) {                                            \
        float4 o = ACC;                                                    \
        if constexpr (SILU) {                                              \
            o.x = o.x / (1.f + expf(-o.x)); o.y = o.y / (1.f + expf(-o.y));\
            o.z = o.z / (1.f + expf(-o.z)); o.w = o.w / (1.f + expf(-o.w));\
        }                                                                  \
        *reinterpret_cast<float4*>(C + (size_t)(r0 + P) * NOUT + c0) = o;  \
    }
    STORE_ROW(0, acc0) STORE_ROW(1, acc1) STORE_ROW(2, acc2) STORE_ROW(3, acc3)
    STORE_ROW(4, acc4) STORE_ROW(5, acc5) STORE_ROW(6, acc6) STORE_ROW(7, acc7)
#undef STORE_ROW
}

// ---------------------------------------------------------------------------
// Dual GEMM sharing A reads: CU = A@WU, CV = A@WV  (A [M,128], W [128,128])
// Same design: WU/WV chunks in LDS; 8 rows x 4 cols x 2 outputs per thread.
__global__ __launch_bounds__(256, 4) void k_uv(const float* __restrict__ A,
                                               const float* __restrict__ WU,
                                               const float* __restrict__ WV,
                                               float* __restrict__ CU,
                                               float* __restrict__ CV, int M) {
    __shared__ float WUs[32 * 132];
    __shared__ float WVs[32 * 132];
    const int tid = threadIdx.x;
    const int cg = tid & 31, rg = tid >> 5;
    const int c0 = cg * 4;
    const int r0 = blockIdx.x * 64 + rg * 8;
    float4 u0, u1, u2, u3, u4, u5, u6, u7;
    float4 q0, q1, q2, q3, q4, q5, q6, q7;
    {
        float4 zz = make_float4(0.f, 0.f, 0.f, 0.f);
        u0 = zz; u1 = zz; u2 = zz; u3 = zz; u4 = zz; u5 = zz; u6 = zz; u7 = zz;
        q0 = zz; q1 = zz; q2 = zz; q3 = zz; q4 = zz; q5 = zz; q6 = zz; q7 = zz;
    }
    for (int kc = 0; kc < 128; kc += 32) {
        __syncthreads();
        for (int idx = tid; idx < 32 * 128; idx += 256) {
            int kk = idx >> 7, c = idx & 127;
            WUs[kk * 132 + c] = WU[(size_t)(kc + kk) * 128 + c];
            WVs[kk * 132 + c] = WV[(size_t)(kc + kk) * 128 + c];
        }
        __syncthreads();
        const float* a0 = A + (size_t)min(r0 + 0, M - 1) * 128 + kc;
        const float* a1 = A + (size_t)min(r0 + 1, M - 1) * 128 + kc;
        const float* a2 = A + (size_t)min(r0 + 2, M - 1) * 128 + kc;
        const float* a3 = A + (size_t)min(r0 + 3, M - 1) * 128 + kc;
        const float* a4 = A + (size_t)min(r0 + 4, M - 1) * 128 + kc;
        const float* a5 = A + (size_t)min(r0 + 5, M - 1) * 128 + kc;
        const float* a6 = A + (size_t)min(r0 + 6, M - 1) * 128 + kc;
        const float* a7 = A + (size_t)min(r0 + 7, M - 1) * 128 + kc;
#pragma unroll 4
        for (int kk = 0; kk < 32; kk++) {
            float4 wu = *reinterpret_cast<const float4*>(&WUs[kk * 132 + c0]);
            float4 wv = *reinterpret_cast<const float4*>(&WVs[kk * 132 + c0]);
            float v0 = a0[kk], v1 = a1[kk], v2 = a2[kk], v3 = a3[kk];
            float v4 = a4[kk], v5 = a5[kk], v6 = a6[kk], v7 = a7[kk];
            u0.x += v0 * wu.x; u0.y += v0 * wu.y; u0.z += v0 * wu.z; u0.w += v0 * wu.w;
            u1.x += v1 * wu.x; u1.y += v1 * wu.y; u1.z += v1 * wu.z; u1.w += v1 * wu.w;
            u2.x += v2 * wu.x; u2.y += v2 * wu.y; u2.z += v2 * wu.z; u2.w += v2 * wu.w;
            u3.x += v3 * wu.x; u3.y += v3 * wu.y; u3.z += v3 * wu.z; u3.w += v3 * wu.w;
            u4.x += v4 * wu.x; u4.y += v4 * wu.y; u4.z += v4 * wu.z; u4.w += v4 * wu.w;
            u5.x += v5 * wu.x; u5.y += v5 * wu.y; u5.z += v5 * wu.z; u5.w += v5 * wu.w;
            u6.x += v6 * wu.x; u6.y += v6 * wu.y; u6.z += v6 * wu.z; u6.w += v6 * wu.w;
            u7.x += v7 * wu.x; u7.y += v7 * wu.y; u7.z += v7 * wu.z; u7.w += v7 * wu.w;
            q0.x += v0 * wv.x; q0.y += v0 * wv.y; q0.z += v0 * wv.z; q0.w += v0 * wv.w;
            q1.x += v1 * wv.x; q1.y += v1 * wv.y; q1.z += v1 * wv.z; q1.w += v1 * wv.w;
            q2.x += v2 * wv.x; q2.y += v2 * wv.y; q2.z += v2 * wv.z; q2.w += v2 * wv.w;
            q3.x += v3 * wv.x; q3.y += v3 * wv.y; q3.z += v3 * wv.z; q3.w += v3 * wv.w;
            q4.x += v4 * wv.x; q4.y += v4 * wv.y; q4.z += v4 * wv.z; q4.w += v4 * wv.w;
            q5.x += v5 * wv.x; q5.y += v5 * wv.y; q5.z += v5 * wv.z; q5.w += v5 * wv.w;
            q6.x += v6 * wv.x; q6.y += v6 * wv.y; q6.z += v6 * wv.z; q6.w += v6 * wv.w;
            q7.x += v7 * wv.x; q7.y += v7 * wv.y; q7.z += v7 * wv.z; q7.w += v7 * wv.w;
        }
    }
#define STORE_UV(P, UA, QA)                                                    \
    if (r0 + P < M) {                                                         \
        *reinterpret_cast<float4*>(CU + (size_t)(r0 + P) * 128 + c0) = UA;    \
        *reinterpret_cast<float4*>(CV + (size_t)(r0 + P) * 128 + c0) = QA;    \
    }
    STORE_UV(0, u0, q0) STORE_UV(1, u1, q1) STORE_UV(2, u2, q2) STORE_UV(3, u3, q3)
    STORE_UV(4, u4, q4) STORE_UV(5, u5, q5) STORE_UV(6, u6, q6) STORE_UV(7, u7, q7)
#undef STORE_UV
}

// ---------------------------------------------------------------------------
// Node-centric edge aggregation, no atomics. One wave per node, full 384
// features; 4-edge unroll so each sW read feeds 4 FMAs (round-7 was 1:2,
// LDS-issue-bound at 41% VALU). Tail edges padded via cut=0 (clamped index).
#define CSTEP(RA, RB, RC, RD, ROW)                                            \
    {                                                                         \
        const float* swr = &sW[(ROW) * F3 + lane];                            \
        float wv;                                                             \
        wv = swr[0];   w0.x += (RA)*wv; w0.y += (RB)*wv; w0.z += (RC)*wv; w0.w += (RD)*wv; \
        wv = swr[64];  w1.x += (RA)*wv; w1.y += (RB)*wv; w1.z += (RC)*wv; w1.w += (RD)*wv; \
        wv = swr[128]; w2.x += (RA)*wv; w2.y += (RB)*wv; w2.z += (RC)*wv; w2.w += (RD)*wv; \
        wv = swr[192]; w3.x += (RA)*wv; w3.y += (RB)*wv; w3.z += (RC)*wv; w3.w += (RD)*wv; \
        wv = swr[256]; w4.x += (RA)*wv; w4.y += (RB)*wv; w4.z += (RC)*wv; w4.w += (RD)*wv; \
        wv = swr[320]; w5.x += (RA)*wv; w5.y += (RB)*wv; w5.z += (RC)*wv; w5.w += (RD)*wv; \
    }

#define EDGE_EPI(WSEL, JV, CD)                                                \
    {                                                                         \
        const size_t pb = (size_t)(JV) * F3 + lane;                           \
        const float cc = (CD).x;                                              \
        const float pw0 = phi[pb]       * (w0.WSEL * cc);                     \
        const float pw1 = phi[pb + 64]  * (w1.WSEL * cc);                     \
        const float pw2 = phi[pb + 128] * (w2.WSEL * cc);                     \
        const float pw3 = phi[pb + 192] * (w3.WSEL * cc);                     \
        const float pw4 = phi[pb + 256] * (w4.WSEL * cc);                     \
        const float pw5 = phi[pb + 320] * (w5.WSEL * cc);                     \
        as0 += pw2; as1 += pw3;                                               \
        ad00 += vold[pb]       * pw0 + pw4 * (CD).y;                          \
        ad01 += vold[pb + 64]  * pw1 + pw5 * (CD).y;                          \
        ad10 += vold[pb + 128] * pw0 + pw4 * (CD).z;                          \
        ad11 += vold[pb + 192] * pw1 + pw5 * (CD).z;                          \
        ad20 += vold[pb + 256] * pw0 + pw4 * (CD).w;                          \
        ad21 += vold[pb + 320] * pw1 + pw5 * (CD).w;                          \
    }

__global__ __launch_bounds__(512, 4) void k_edge_node(const int* __restrict__ rowstart,
                                                      const int* __restrict__ j_csr,
                                                      const float4* __restrict__ cd_csr,
                                                      const float* __restrict__ rbf_csr,
                                                      const float* __restrict__ phi,
                                                      const float* __restrict__ vold,
                                                      const float* __restrict__ rbf_w,
                                                      const float* __restrict__ rbf_b,
                                                      float* __restrict__ sfeat,
                                                      float* __restrict__ vnew) {
    __shared__ float sW[RR * F3 + F3];   // weights rows 0..19, bias row 20: 31.5 KB
    for (int idx = threadIdx.x; idx < RR * F3; idx += 512) sW[idx] = rbf_w[idx];
    for (int idx = threadIdx.x; idx < F3; idx += 512) sW[RR * F3 + idx] = rbf_b[idx];
    __syncthreads();
    const int wave = threadIdx.x >> 6, lane = threadIdx.x & 63;
    const int n = blockIdx.x * 8 + wave;       // grid.x*8 == NN exactly
    float as0 = 0.f, as1 = 0.f;
    float ad00 = 0.f, ad01 = 0.f, ad10 = 0.f, ad11 = 0.f, ad20 = 0.f, ad21 = 0.f;
    const float bb0 = sW[RR * F3 + lane];
    const float bb1 = sW[RR * F3 + 64 + lane];
    const float bb2 = sW[RR * F3 + 128 + lane];
    const float bb3 = sW[RR * F3 + 192 + lane];
    const float bb4 = sW[RR * F3 + 256 + lane];
    const float bb5 = sW[RR * F3 + 320 + lane];
    const int t1 = rowstart[n + 1];
    for (int t = rowstart[n]; t < t1; t += 4) {
        const int i0 = t;
        const int i1 = (t + 1 < t1) ? t + 1 : t;
        const int i2 = (t + 2 < t1) ? t + 2 : t;
        const int i3 = (t + 3 < t1) ? t + 3 : t;
        const int j0 = j_csr[i0], j1 = j_csr[i1], j2 = j_csr[i2], j3 = j_csr[i3];
        const float4 cd0 = cd_csr[i0];
        const float4 cd1 = (t + 1 < t1) ? cd_csr[i1] : make_float4(0.f, 0.f, 0.f, 0.f);
        const float4 cd2 = (t + 2 < t1) ? cd_csr[i2] : make_float4(0.f, 0.f, 0.f, 0.f);
        const float4 cd3 = (t + 3 < t1) ? cd_csr[i3] : make_float4(0.f, 0.f, 0.f, 0.f);
        const float* rp0 = rbf_csr + (size_t)i0 * RR;
        const float* rp1 = rbf_csr + (size_t)i1 * RR;
        const float* rp2 = rbf_csr + (size_t)i2 * RR;
        const float* rp3 = rbf_csr + (size_t)i3 * RR;
        float4 w0 = make_float4(bb0, bb0, bb0, bb0);
        float4 w1 = make_float4(bb1, bb1, bb1, bb1);
        float4 w2 = make_float4(bb2, bb2, bb2, bb2);
        float4 w3 = make_float4(bb3, bb3, bb3, bb3);
        float4 w4 = make_float4(bb4, bb4, bb4, bb4);
        float4 w5 = make_float4(bb5, bb5, bb5, bb5);
#pragma unroll
        for (int q = 0; q < 5; q++) {
            const float4 ra = *reinterpret_cast<const float4*>(rp0 + q * 4);
            const float4 rb = *reinterpret_cast<const float4*>(rp1 + q * 4);
            const float4 rc = *reinterpret_cast<const float4*>(rp2 + q * 4);
            const float4 rd = *reinterpret_cast<const float4*>(rp3 + q * 4);
            CSTEP(ra.x, rb.x, rc.x, rd.x, 4 * q + 0)
            CSTEP(ra.y, rb.y, rc.y, rd.y, 4 * q + 1)
            CSTEP(ra.z, rb.z, rc.z, rd.z, 4 * q + 2)
            CSTEP(ra.w, rb.w, rc.w, rd.w, 4 * q + 3)
        }
        EDGE_EPI(x, j0, cd0)
        EDGE_EPI(y, j1, cd1)
        EDGE_EPI(z, j2, cd2)
        EDGE_EPI(w, j3, cd3)
    }
    sfeat[n * FF + lane]      += as0;          // node owned by this wave: no atomics
    sfeat[n * FF + 64 + lane] += as1;
    const size_t vb0 = (size_t)n * F3 + lane;
    vnew[vb0]       = vold[vb0]       + ad00;
    vnew[vb0 + 64]  = vold[vb0 + 64]  + ad01;
    vnew[vb0 + 128] = vold[vb0 + 128] + ad10;
    vnew[vb0 + 192] = vold[vb0 + 192] + ad11;
    vnew[vb0 + 256] = vold[vb0 + 256] + ad20;
    vnew[vb0 + 320] = vold[vb0 + 320] + ad21;
}

// ---------------------------------------------------------------------------
// per (n,g): vnorm = safe_norm(Vv[n,:,g]), dot = <Uv,Vv>
__global__ __launch_bounds__(256) void k_normdot(const float* __restrict__ Uv,
                                                 const float* __restrict__ Vv,
                                                 float* __restrict__ vnorm,
                                                 float* __restrict__ dotb) {
    int idx = blockIdx.x * 256 + threadIdx.x;
    if (idx >= NN * FF) return;
    int n = idx >> 7, g = idx & 127;
    const float* uv = Uv + (size_t)n * F3 + g;
    const float* vv = Vv + (size_t)n * F3 + g;
    float u0 = uv[0], u1 = uv[FF], u2 = uv[2 * FF];
    float w0 = vv[0], w1 = vv[FF], w2 = vv[2 * FF];
    float sq = w0 * w0 + w1 * w1 + w2 * w2;
    vnorm[idx] = sq > 0.f ? sqrtf(sq) : 0.f;
    dotb[idx] = u0 * w0 + u1 * w1 + u2 * w2;
}

// ---------------------------------------------------------------------------
// gated update: v[n,:,g] += Uv[n,:,g]*a_vv;  s[n,g] += a_ss + a_sv*dot
__global__ __launch_bounds__(256) void k_update(const float* __restrict__ a,
                                                const float* __restrict__ Uv,
                                                const float* __restrict__ dotb,
                                                float* __restrict__ v,
                                                float* __restrict__ sfeat) {
    int idx = blockIdx.x * 256 + threadIdx.x;
    if (idx >= NN * FF) return;
    int n = idx >> 7, g = idx & 127;
    float avv = a[(size_t)n * F3 + g];
    float asv = a[(size_t)n * F3 + 128 + g];
    float ass = a[(size_t)n * F3 + 256 + g];
#pragma unroll
    for (int d = 0; d < 3; d++)
        v[(size_t)n * F3 + d * FF + g] += Uv[(size_t)n * F3 + d * FF + g] * avv;
    sfeat[idx] += ass + asv * dotb[idx];
}

// ---------------------------------------------------------------------------
// transpose internal v[N,3,F] -> output vfeat[N,F,3]
__global__ __launch_bounds__(256) void k_outv(const float* __restrict__ v,
                                              float* __restrict__ outv) {
    int idx = blockIdx.x * 256 + threadIdx.x;
    if (idx >= NN * FF * 3) return;
    int n = idx / F3;
    int rem = idx - n * F3;
    int f = rem / 3;
    int d = rem - f * 3;
    outv[idx] = v[n * F3 + d * FF + f];
}

// ---------------------------------------------------------------------------
extern "C" void kernel_launch(void* const* d_in, const int* in_sizes, int n_in,
                              void* d_out, int out_size, void* d_ws, size_t ws_size,
                              hipStream_t stream) {
    const int*   z      = (const int*)d_in[0];
    const float* pos    = (const float*)d_in[1];
    const int*   idx_i  = (const int*)d_in[2];
    const int*   idx_j  = (const int*)d_in[3];
    const float* emb    = (const float*)d_in[4];
    const float* msg_w1 = (const float*)d_in[5];
    const float* msg_b1 = (const float*)d_in[6];
    const float* msg_w2 = (const float*)d_in[7];
    const float* msg_b2 = (const float*)d_in[8];
    const float* rbf_w  = (const float*)d_in[9];
    const float* rbf_b  = (const float*)d_in[10];
    const float* upd_U  = (const float*)d_in[11];
    const float* upd_V  = (const float*)d_in[12];
    const float* upd_w1 = (const float*)d_in[13];
    const float* upd_b1 = (const float*)d_in[14];
    const float* upd_w2 = (const float*)d_in[15];
    const float* upd_b2 = (const float*)d_in[16];

    float* sfeat = (float*)d_out;            // [N,F]
    float* outv  = sfeat + NN * FF;          // [N,F,3]

    float* ws    = (float*)d_ws;
    float* va    = ws;                       // [N,3,F] ping
    float* vb    = va + NN * F3;             // [N,3,F] pong
    float* phi   = vb + NN * F3;             // [N,3F] (also reused as 'a')
    float* h     = phi + NN * F3;            // [N,F]
    float* Uvb   = h + NN * FF;              // [N,3,F]
    float* Vvb   = Uvb + NN * F3;            // [N,3,F]
    float* vnorm = Vvb + NN * F3;            // [N,F]
    float* dotb  = vnorm + NN * FF;          // [N,F]
    float4* cd_csr = (float4*)(dotb + NN * FF);   // [E] (all offsets %4==0 -> 16B ok)
    float* rbf_csr = (float*)(cd_csr + EE);       // [E,R]
    int*   j_csr     = (int*)(rbf_csr + (size_t)EE * RR);  // [E]
    int*   deg       = j_csr + EE;           // [N]
    int*   rowstart  = deg + NN;             // [N+1]
    int*   cursor    = rowstart + NN + 1;    // [N]
    int*   eids      = cursor + NN;          // [E]

    const dim3 blk(256);
    const dim3 gE((EE + 255) / 256);
    k_init<<<dim3((NN * 3 * FF) / 256), blk, 0, stream>>>(z, emb, sfeat, va, deg);
    k_count<<<gE, blk, 0, stream>>>(idx_i, idx_j, pos, deg);
    k_scan<<<dim3(1), dim3(1024), 0, stream>>>(deg, rowstart, cursor);
    k_fill<<<gE, blk, 0, stream>>>(idx_i, idx_j, pos, cursor, eids);
    k_permute<<<gE, blk, 0, stream>>>(idx_i, idx_j, pos, eids, rowstart,
                                      j_csr, cd_csr, rbf_csr);

    float* vcur = va;
    float* vnxt = vb;
    const int gN32  = (NN + 31) / 32;        // 313
    const int gN64  = (NN + 63) / 64;        // 157
    const int g3N64 = (3 * NN + 63) / 64;    // 469

    for (int l = 0; l < LL; l++) {
        const float* mw1 = msg_w1 + l * FF * FF;
        const float* mb1 = msg_b1 + l * FF;
        const float* mw2 = msg_w2 + l * FF * F3;
        const float* mb2 = msg_b2 + l * F3;
        const float* rw  = rbf_w + l * RR * F3;
        const float* rb  = rbf_b + l * F3;
        const float* uU  = upd_U + l * FF * FF;
        const float* uV  = upd_V + l * FF * FF;
        const float* uw1 = upd_w1 + l * 2 * FF * FF;
        const float* ub1 = upd_b1 + l * FF;
        const float* uw2 = upd_w2 + l * FF * F3;
        const float* ub2 = upd_b2 + l * F3;

        // h = silu(s@w1+b1); phi = h@w2+b2
        k_mlp<128, 32, true><<<dim3(gN32, 1), blk, 0, stream>>>(sfeat, 128, nullptr, mw1, mb1, h, NN, 128);
        k_mlp<128, 64, false><<<dim3(gN64, 3), blk, 0, stream>>>(h, 128, nullptr, mw2, mb2, phi, NN, F3);

        // node-centric message aggregation: sfeat += ..., vnxt = vcur + dv
        k_edge_node<<<dim3(NN / 8), dim3(512), 0, stream>>>(rowstart, j_csr, cd_csr, rbf_csr,
                                                            phi, vcur, rw, rb, sfeat, vnxt);

        // Uv/Vv dual GEMM on vnxt
        k_uv<<<dim3(g3N64), blk, 0, stream>>>(vnxt, uU, uV, Uvb, Vvb, 3 * NN);
        k_normdot<<<dim3((NN * FF) / 256), blk, 0, stream>>>(Uvb, Vvb, vnorm, dotb);

        // h = silu([vnorm|sfeat]@w1+b1); a = h@w2+b2 (into phi buffer)
        k_mlp<256, 32, true><<<dim3(gN32, 1), blk, 0, stream>>>(vnorm, 128, sfeat, uw1, ub1, h, NN, 128);
        k_mlp<128, 64, false><<<dim3(gN64, 3), blk, 0, stream>>>(h, 128, nullptr, uw2, ub2, phi, NN, F3);

        // gating epilogue (updates vnxt, sfeat)
        k_update<<<dim3((NN * FF) / 256), blk, 0, stream>>>(phi, Uvb, dotb, vnxt, sfeat);

        // ping-pong
        float* tmp = vcur; vcur = vnxt; vnxt = tmp;
    }

    k_outv<<<dim3((NN * FF * 3 + 255) / 256), blk, 0, stream>>>(vcur, outv);
}